// Round 1
// baseline (535.288 us; speedup 1.0000x reference)
//
#include <hip/hip_runtime.h>

typedef short bf16x8 __attribute__((ext_vector_type(8)));
typedef float f32x4 __attribute__((ext_vector_type(4)));

__device__ __forceinline__ unsigned short f2b(float f){
  union { float f; unsigned u; } v; v.f = f;
  unsigned r = v.u + 0x7FFFu + ((v.u >> 16) & 1u);
  return (unsigned short)(r >> 16);
}
__device__ __forceinline__ float b2f(unsigned short s){
  union { unsigned u; float f; } v; v.u = ((unsigned)s) << 16;
  return v.f;
}

// ---------------- precompute: Qm/Km/Vm = FE @ W_in^T  (3 x 64 x 256) ----------------
__global__ void k_pre_qkv(const float* __restrict__ FE, const float* __restrict__ W_in,
                          float* __restrict__ Qm, float* __restrict__ Km, float* __restrict__ Vm){
  int id = blockIdx.x*256 + threadIdx.x;      // 49152 = 3*64*256
  int part = id >> 14;
  int l = (id >> 8) & 63;
  int d = id & 255;
  const float4* fe = (const float4*)(FE + l*256);
  const float4* wr = (const float4*)(W_in + (part*256 + d)*256);
  float s = 0.f;
  #pragma unroll 8
  for (int k=0;k<64;k++){
    float4 a = fe[k], b = wr[k];
    s += a.x*b.x + a.y*b.y + a.z*b.z + a.w*b.w;
  }
  float* dst = (part==0)?Qm:((part==1)?Km:Vm);
  dst[l*256+d] = s;
}

// ---------------- precompute: G,u,w,s, abias ----------------
__global__ void k_pre_att(const float* __restrict__ Qm, const float* __restrict__ Km,
                          const float* __restrict__ b_in, const float* __restrict__ W_ao,
                          const float* __restrict__ b_ao,
                          float* __restrict__ G, float* __restrict__ U,
                          float* __restrict__ W, float* __restrict__ S,
                          float* __restrict__ abias){
  int id = blockIdx.x*256 + threadIdx.x;
  const float inv = 0.17677669529663687f;   // 1/sqrt(32)
  if (id < 32768){
    int h = id >> 12, lq = (id>>6)&63, lk = id&63;
    const float* qp = Qm + lq*256 + h*32;
    const float* kp = Km + lk*256 + h*32;
    float s=0.f;
    #pragma unroll
    for (int d=0;d<32;d++) s += qp[d]*kp[d];
    G[id] = s*inv;
  } else if (id < 33280){
    int j = id - 32768; int h = j>>6, lq = j&63;
    const float* qp = Qm + lq*256 + h*32;
    const float* bk = b_in + 256 + h*32;
    float s=0.f;
    #pragma unroll
    for (int d=0;d<32;d++) s += qp[d]*bk[d];
    U[j] = s*inv;
  } else if (id < 33792){
    int j = id - 33280; int h = j>>6, lk = j&63;
    const float* kp = Km + lk*256 + h*32;
    const float* bq = b_in + h*32;
    float s=0.f;
    #pragma unroll
    for (int d=0;d<32;d++) s += bq[d]*kp[d];
    W[j] = s*inv;
  } else if (id < 33800){
    int h = id - 33792;
    float s=0.f;
    #pragma unroll
    for (int d=0;d<32;d++) s += b_in[h*32+d]*b_in[256+h*32+d];
    S[h] = s*inv;
  } else if (id < 34056){
    int e = id - 33800;
    float s = b_ao[e];
    for (int d=0; d<256; d++) s += b_in[512+d]*W_ao[e*256+d];
    abias[e] = s;
  }
}

// ---------------- precompute: M2t[e][h*64+lk] = sum_d Vm[lk][h*32+d]*W_ao[e][h*32+d] ----------------
__global__ void k_pre_m2t(const float* __restrict__ Vm, const float* __restrict__ W_ao,
                          short* __restrict__ M2t){
  int id = blockIdx.x*256 + threadIdx.x;   // 131072 = 256*512
  int e = id >> 9, kk = id & 511;
  int h = kk >> 6, lk = kk & 63;
  const float* vp = Vm + lk*256 + h*32;
  const float* wp = W_ao + e*256 + h*32;
  float s=0.f;
  #pragma unroll
  for (int d=0;d<32;d++) s += vp[d]*wp[d];
  M2t[id] = (short)f2b(s);
}

// ---------------- precompute: bf16 weight copies ----------------
__global__ void k_cvt(const float* __restrict__ W1, const float* __restrict__ W2,
                      short* __restrict__ W1b, short* __restrict__ W2b){
  int id = blockIdx.x*256 + threadIdx.x;   // 524288
  if (id < 262144) W1b[id] = (short)f2b(W1[id]);
  else             W2b[id-262144] = (short)f2b(W2[id-262144]);
}

// ---------------- RNN scan + fourier -> z  (16 blocks x 64 threads) ----------------
__global__ void k_rnn(const float* __restrict__ x_cont, const float* __restrict__ z0,
                      const float* __restrict__ W_ih, const float* __restrict__ W_hh,
                      const float* __restrict__ b_ih, const float* __restrict__ b_hh,
                      const float* __restrict__ Uf, const float* __restrict__ Wfp,
                      const float* __restrict__ bfp, float* __restrict__ zout){
  int b = blockIdx.x;
  int l = threadIdx.x;
  __shared__ float h_sh[64];
  __shared__ float fh_sh[24];
  __shared__ float WfpT[24][64];
  float wr[64];
  #pragma unroll
  for (int j=0;j<64;j++) wr[j] = W_hh[l*64+j];
  #pragma unroll
  for (int j=0;j<24;j++) WfpT[j][l] = Wfp[l*24+j];
  float wih = W_ih[l];
  float bb  = b_ih[l] + b_hh[l];
  float bf  = bfp[l];
  float uf0=0,uf1=0,uf2=0,uf3=0;
  if (l < 24){ uf0=Uf[l*4+0]; uf1=Uf[l*4+1]; uf2=Uf[l*4+2]; uf3=Uf[l*4+3]; }
  h_sh[l] = z0[l];
  __syncthreads();
  const float* xb = x_cont + (size_t)b*128*97;
  for (int t=0;t<128;t++){
    float x0 = xb[t*97];
    float a0=0,a1=0,a2=0,a3=0;
    #pragma unroll
    for (int j=0;j<64;j+=4){
      a0 += wr[j  ]*h_sh[j  ];
      a1 += wr[j+1]*h_sh[j+1];
      a2 += wr[j+2]*h_sh[j+2];
      a3 += wr[j+3]*h_sh[j+3];
    }
    float hn = fmaxf(x0*wih + bb + ((a0+a1)+(a2+a3)), 0.f);
    float fh = 0.f;
    if (l < 24){
      const float* xf = xb + t*97 + 1 + l*4;
      fh = xf[0]*uf0 + xf[1]*uf1 + xf[2]*uf2 + xf[3]*uf3;
    }
    __syncthreads();
    h_sh[l] = hn;
    if (l < 24) fh_sh[l] = fh;
    __syncthreads();
    float zv = hn + bf;
    #pragma unroll
    for (int j=0;j<24;j++) zv += fh_sh[j]*WfpT[j][l];
    zout[((size_t)b*128 + t)*64 + l] = zv;
  }
}

// ---------------- fused per-token transformer block (2048 blocks x 256 thr) ----------------
__global__ __launch_bounds__(256, 2) void k_main(
  const float* __restrict__ zall, const float* __restrict__ G,
  const float* __restrict__ Ubuf, const float* __restrict__ Wbuf, const float* __restrict__ Sbuf,
  const float* __restrict__ abias, const short* __restrict__ M2t,
  const float* __restrict__ FE,
  const short* __restrict__ W1b, const float* __restrict__ b1,
  const short* __restrict__ W2b, const float* __restrict__ b2,
  const float* __restrict__ g1, const float* __restrict__ be1,
  const float* __restrict__ g2, const float* __restrict__ be2,
  const float* __restrict__ Wop, const float* __restrict__ bop,
  const float* __restrict__ Wg, const float* __restrict__ bg,
  const float* __restrict__ Amat, const float* __restrict__ cvec,
  float* __restrict__ out)
{
  const int n = blockIdx.x;
  const int tid = threadIdx.x;
  const int w = tid >> 6, lane = tid & 63, lg = lane >> 4, lr = lane & 15;
  const int cb = w * 64;

  __shared__ float z_sh[64], gate_sh[64], zout_sh[64];
  __shared__ float redA[4][64], redB[4][64];
  __shared__ short attz_sh[64][72];     // stride 144B -> 2-way banks (free)
  __shared__ short t1_sh[64][264];      // stride 528B -> 2-way banks
  __shared__ short mid_sh[64][264];

  if (tid < 64) z_sh[tid] = zall[n*64 + tid];
  __syncthreads();

  const int lq = tid >> 2, q = tid & 3;

  // gate = sigmoid(z @ Wg^T + bg)   (4 lanes per row)
  {
    float p = 0.f;
    const float* wg = Wg + lq*64 + q*16;
    #pragma unroll
    for (int i=0;i<16;i++) p += z_sh[q*16+i]*wg[i];
    p += __shfl_xor(p, 1);
    p += __shfl_xor(p, 2);
    if (q == 0) gate_sh[lq] = 1.f/(1.f + __expf(-(p + bg[lq])));
  }

  // ---------- attention + fused V/out-proj:  aop = attz @ M2t^T ----------
  f32x4 acc[4][4];
  #pragma unroll
  for (int m=0;m<4;m++)
    #pragma unroll
    for (int nt=0;nt<4;nt++){ f32x4 zz = {0.f,0.f,0.f,0.f}; acc[m][nt] = zz; }

  const float zq = z_sh[lq];

  for (int h=0; h<8; h++){
    float e[16];
    {
      const float* Gp = G + ((h*64 + lq)*64 + q*16);
      const float uh = Ubuf[h*64 + lq];
      const float sh = Sbuf[h];
      const float* wp = Wbuf + h*64 + q*16;
      float mx = -1e30f;
      #pragma unroll
      for (int i=0;i<16;i++){
        float zk = z_sh[q*16+i];
        float lv = zq*(zk*Gp[i] + uh) + (zk*wp[i] + sh);
        e[i] = lv;
        mx = fmaxf(mx, lv);
      }
      mx = fmaxf(mx, __shfl_xor(mx,1));
      mx = fmaxf(mx, __shfl_xor(mx,2));
      float sum = 0.f;
      #pragma unroll
      for (int i=0;i<16;i++){ e[i] = __expf(e[i]-mx); sum += e[i]; }
      sum += __shfl_xor(sum,1);
      sum += __shfl_xor(sum,2);
      float inv = 1.f/sum;
      #pragma unroll
      for (int i=0;i<16;i++) e[i] = e[i]*inv*z_sh[q*16+i];
    }
    __syncthreads();   // previous head's MFMA reads of attz_sh complete
    {
      bf16x8 v0, v1;
      #pragma unroll
      for (int i=0;i<8;i++){ v0[i] = (short)f2b(e[i]); v1[i] = (short)f2b(e[8+i]); }
      *(bf16x8*)&attz_sh[lq][q*16]     = v0;
      *(bf16x8*)&attz_sh[lq][q*16 + 8] = v1;
    }
    __syncthreads();
    #pragma unroll
    for (int ks=0; ks<2; ks++){
      bf16x8 a[4], bfr[4];
      #pragma unroll
      for (int m=0;m<4;m++) a[m] = *(const bf16x8*)&attz_sh[m*16+lr][ks*32 + lg*8];
      #pragma unroll
      for (int nt=0;nt<4;nt++){
        int e_ = cb + nt*16 + lr;
        bfr[nt] = *(const bf16x8*)(M2t + e_*512 + h*64 + ks*32 + lg*8);
      }
      #pragma unroll
      for (int m=0;m<4;m++)
        #pragma unroll
        for (int nt=0;nt<4;nt++)
          acc[m][nt] = __builtin_amdgcn_mfma_f32_16x16x32_bf16(a[m], bfr[nt], acc[m][nt], 0,0,0);
    }
  }

  // ---------- t1 = LN(tokens + aop) ----------
  float g1v[4], be1v[4], abv[4];
  #pragma unroll
  for (int nt=0;nt<4;nt++){
    int col = cb + nt*16 + lr;
    abv[nt] = abias[col]; g1v[nt] = g1[col]; be1v[nt] = be1[col];
  }
  #pragma unroll
  for (int m=0;m<4;m++){
    #pragma unroll
    for (int r=0;r<4;r++){
      int row = m*16 + lg*4 + r;
      float zr = z_sh[row];
      float s = 0.f;
      #pragma unroll
      for (int nt=0;nt<4;nt++){
        int col = cb + nt*16 + lr;
        float v = acc[m][nt][r] + abv[nt] + zr*FE[row*256 + col];
        acc[m][nt][r] = v; s += v;
      }
      s += __shfl_xor(s,1); s += __shfl_xor(s,2); s += __shfl_xor(s,4); s += __shfl_xor(s,8);
      if (lr == 0) redA[w][row] = s;
    }
  }
  __syncthreads();
  float mu[4][4], rs[4][4];
  #pragma unroll
  for (int m=0;m<4;m++)
    #pragma unroll
    for (int r=0;r<4;r++){
      int row = m*16 + lg*4 + r;
      mu[m][r] = (redA[0][row]+redA[1][row]+redA[2][row]+redA[3][row])*(1.f/256.f);
    }
  #pragma unroll
  for (int m=0;m<4;m++){
    #pragma unroll
    for (int r=0;r<4;r++){
      int row = m*16 + lg*4 + r;
      float s = 0.f;
      #pragma unroll
      for (int nt=0;nt<4;nt++){ float d = acc[m][nt][r]-mu[m][r]; s += d*d; }
      s += __shfl_xor(s,1); s += __shfl_xor(s,2); s += __shfl_xor(s,4); s += __shfl_xor(s,8);
      if (lr == 0) redB[w][row] = s;
    }
  }
  __syncthreads();
  #pragma unroll
  for (int m=0;m<4;m++)
    #pragma unroll
    for (int r=0;r<4;r++){
      int row = m*16 + lg*4 + r;
      rs[m][r] = rsqrtf((redB[0][row]+redB[1][row]+redB[2][row]+redB[3][row])*(1.f/256.f) + 1e-5f);
    }
  #pragma unroll
  for (int m=0;m<4;m++)
    #pragma unroll
    for (int r=0;r<4;r++){
      int row = m*16 + lg*4 + r;
      #pragma unroll
      for (int nt=0;nt<4;nt++){
        int col = cb + nt*16 + lr;
        float t = (acc[m][nt][r]-mu[m][r])*rs[m][r]*g1v[nt] + be1v[nt];
        t1_sh[row][col] = (short)f2b(t);
      }
    }
  __syncthreads();

  // ---------- FFN: out = relu(t1@W1^T + b1)@W2^T (chunked over 4D) ----------
  f32x4 outv[4][4];
  #pragma unroll
  for (int m=0;m<4;m++)
    #pragma unroll
    for (int nt=0;nt<4;nt++){ f32x4 zz = {0.f,0.f,0.f,0.f}; outv[m][nt] = zz; }

  for (int ch=0; ch<4; ch++){
    f32x4 midv[4][4];
    #pragma unroll
    for (int nt=0;nt<4;nt++){
      float bv = b1[ch*256 + cb + nt*16 + lr];
      f32x4 b4 = {bv,bv,bv,bv};
      #pragma unroll
      for (int m=0;m<4;m++) midv[m][nt] = b4;
    }
    #pragma unroll
    for (int ks=0; ks<8; ks++){
      bf16x8 a[4], bb[4];
      #pragma unroll
      for (int m=0;m<4;m++) a[m] = *(const bf16x8*)&t1_sh[m*16+lr][ks*32 + lg*8];
      #pragma unroll
      for (int nt=0;nt<4;nt++)
        bb[nt] = *(const bf16x8*)(W1b + (size_t)(ch*256 + cb + nt*16 + lr)*256 + ks*32 + lg*8);
      #pragma unroll
      for (int m=0;m<4;m++)
        #pragma unroll
        for (int nt=0;nt<4;nt++)
          midv[m][nt] = __builtin_amdgcn_mfma_f32_16x16x32_bf16(a[m], bb[nt], midv[m][nt], 0,0,0);
    }
    __syncthreads();   // prior chunk's mid_sh reads complete
    #pragma unroll
    for (int m=0;m<4;m++)
      #pragma unroll
      for (int r=0;r<4;r++){
        int row = m*16 + lg*4 + r;
        #pragma unroll
        for (int nt=0;nt<4;nt++){
          int col = cb + nt*16 + lr;
          mid_sh[row][col] = (short)f2b(fmaxf(midv[m][nt][r], 0.f));
        }
      }
    __syncthreads();
    #pragma unroll
    for (int ks=0; ks<8; ks++){
      bf16x8 a[4], bb[4];
      #pragma unroll
      for (int m=0;m<4;m++) a[m] = *(const bf16x8*)&mid_sh[m*16+lr][ks*32 + lg*8];
      #pragma unroll
      for (int nt=0;nt<4;nt++)
        bb[nt] = *(const bf16x8*)(W2b + (size_t)(cb + nt*16 + lr)*1024 + ch*256 + ks*32 + lg*8);
      #pragma unroll
      for (int m=0;m<4;m++)
        #pragma unroll
        for (int nt=0;nt<4;nt++)
          outv[m][nt] = __builtin_amdgcn_mfma_f32_16x16x32_bf16(a[m], bb[nt], outv[m][nt], 0,0,0);
    }
  }

  // ---------- t2 = LN(t1 + ffn), delta, z_out, o ----------
  float b2v[4], g2v[4], be2v[4], wopv[4];
  #pragma unroll
  for (int nt=0;nt<4;nt++){
    int col = cb + nt*16 + lr;
    b2v[nt] = b2[col]; g2v[nt] = g2[col]; be2v[nt] = be2[col]; wopv[nt] = Wop[col];
  }
  __syncthreads();
  #pragma unroll
  for (int m=0;m<4;m++){
    #pragma unroll
    for (int r=0;r<4;r++){
      int row = m*16 + lg*4 + r;
      float s = 0.f;
      #pragma unroll
      for (int nt=0;nt<4;nt++){
        int col = cb + nt*16 + lr;
        float v = outv[m][nt][r] + b2v[nt] + b2f((unsigned short)t1_sh[row][col]);
        outv[m][nt][r] = v; s += v;
      }
      s += __shfl_xor(s,1); s += __shfl_xor(s,2); s += __shfl_xor(s,4); s += __shfl_xor(s,8);
      if (lr == 0) redA[w][row] = s;
    }
  }
  __syncthreads();
  float mu2[4][4], rs2[4][4];
  #pragma unroll
  for (int m=0;m<4;m++)
    #pragma unroll
    for (int r=0;r<4;r++){
      int row = m*16 + lg*4 + r;
      mu2[m][r] = (redA[0][row]+redA[1][row]+redA[2][row]+redA[3][row])*(1.f/256.f);
    }
  #pragma unroll
  for (int m=0;m<4;m++){
    #pragma unroll
    for (int r=0;r<4;r++){
      int row = m*16 + lg*4 + r;
      float s = 0.f;
      #pragma unroll
      for (int nt=0;nt<4;nt++){ float d = outv[m][nt][r]-mu2[m][r]; s += d*d; }
      s += __shfl_xor(s,1); s += __shfl_xor(s,2); s += __shfl_xor(s,4); s += __shfl_xor(s,8);
      if (lr == 0) redB[w][row] = s;
    }
  }
  __syncthreads();
  #pragma unroll
  for (int m=0;m<4;m++)
    #pragma unroll
    for (int r=0;r<4;r++){
      int row = m*16 + lg*4 + r;
      rs2[m][r] = rsqrtf((redB[0][row]+redB[1][row]+redB[2][row]+redB[3][row])*(1.f/256.f) + 1e-5f);
    }
  // delta = t2 @ Wop + bop
  #pragma unroll
  for (int m=0;m<4;m++){
    #pragma unroll
    for (int r=0;r<4;r++){
      int row = m*16 + lg*4 + r;
      float s = 0.f;
      #pragma unroll
      for (int nt=0;nt<4;nt++){
        float t2 = (outv[m][nt][r]-mu2[m][r])*rs2[m][r]*g2v[nt] + be2v[nt];
        s += t2*wopv[nt];
      }
      s += __shfl_xor(s,1); s += __shfl_xor(s,2); s += __shfl_xor(s,4); s += __shfl_xor(s,8);
      if (lr == 0) redA[w][row] = s;
    }
  }
  __syncthreads();
  if (tid < 64){
    int row = tid;
    float delta = redA[0][row]+redA[1][row]+redA[2][row]+redA[3][row] + bop[0];
    float zo = z_sh[row] + gate_sh[row]*delta;
    zout_sh[row] = zo;
    out[49152 + (size_t)n*64 + row] = zo;
  }
  __syncthreads();
  if (tid < 24){
    const float* ar = Amat + tid*64;
    float s = cvec[tid];
    #pragma unroll
    for (int j=0;j<64;j++) s += zout_sh[j]*ar[j];
    out[(size_t)n*24 + tid] = s;
  }
}

extern "C" void kernel_launch(void* const* d_in, const int* in_sizes, int n_in,
                              void* d_out, int out_size, void* d_ws, size_t ws_size,
                              hipStream_t stream) {
  const float* x_cont = (const float*)d_in[0];
  const float* z0    = (const float*)d_in[1];
  const float* W_ih  = (const float*)d_in[2];
  const float* W_hh  = (const float*)d_in[3];
  const float* b_ih  = (const float*)d_in[4];
  const float* b_hh  = (const float*)d_in[5];
  const float* Uf    = (const float*)d_in[6];
  const float* Wfp   = (const float*)d_in[7];
  const float* bfp   = (const float*)d_in[8];
  const float* FE    = (const float*)d_in[9];
  const float* W_in  = (const float*)d_in[10];
  const float* b_in  = (const float*)d_in[11];
  const float* W_ao  = (const float*)d_in[12];
  const float* b_ao  = (const float*)d_in[13];
  const float* g1    = (const float*)d_in[14];
  const float* be1   = (const float*)d_in[15];
  const float* W1    = (const float*)d_in[16];
  const float* b1    = (const float*)d_in[17];
  const float* W2    = (const float*)d_in[18];
  const float* b2    = (const float*)d_in[19];
  const float* g2    = (const float*)d_in[20];
  const float* be2   = (const float*)d_in[21];
  const float* Wop   = (const float*)d_in[22];
  const float* bop   = (const float*)d_in[23];
  const float* Wg    = (const float*)d_in[24];
  const float* bg    = (const float*)d_in[25];
  const float* Amat  = (const float*)d_in[26];
  const float* cvec  = (const float*)d_in[27];
  float* out = (float*)d_out;
  char* ws = (char*)d_ws;

  float* z    = (float*)(ws + 0);         // 2048*64*4
  float* Qm   = (float*)(ws + 524288);
  float* Km   = (float*)(ws + 589824);
  float* Vm   = (float*)(ws + 655360);
  float* G    = (float*)(ws + 720896);    // 8*64*64*4
  float* U    = (float*)(ws + 851968);
  float* Wb   = (float*)(ws + 854016);
  float* S    = (float*)(ws + 856064);
  float* ab   = (float*)(ws + 856320);
  short* M2t  = (short*)(ws + 857344);    // 256*512*2
  short* W1b  = (short*)(ws + 1119488);   // 1024*256*2
  short* W2b  = (short*)(ws + 1643776);   // 256*1024*2

  hipLaunchKernelGGL(k_pre_qkv, dim3(192), dim3(256), 0, stream, FE, W_in, Qm, Km, Vm);
  hipLaunchKernelGGL(k_pre_att, dim3(134), dim3(256), 0, stream, Qm, Km, b_in, W_ao, b_ao, G, U, Wb, S, ab);
  hipLaunchKernelGGL(k_pre_m2t, dim3(512), dim3(256), 0, stream, Vm, W_ao, M2t);
  hipLaunchKernelGGL(k_cvt, dim3(2048), dim3(256), 0, stream, W1, W2, W1b, W2b);
  hipLaunchKernelGGL(k_rnn, dim3(16), dim3(64), 0, stream, x_cont, z0, W_ih, W_hh, b_ih, b_hh, Uf, Wfp, bfp, z);
  hipLaunchKernelGGL(k_main, dim3(2048), dim3(256), 0, stream, z, G, U, Wb, S, ab, M2t, FE,
                     W1b, b1, W2b, b2, g1, be1, g2, be2, Wop, bop, Wg, bg, Amat, cvec, out);
}

// Round 2
// 505.000 us; speedup vs baseline: 1.0600x; 1.0600x over previous
//
#include <hip/hip_runtime.h>

typedef short bf16x8 __attribute__((ext_vector_type(8)));
typedef short s16x4  __attribute__((ext_vector_type(4)));
typedef float f32x4  __attribute__((ext_vector_type(4)));

__device__ __forceinline__ unsigned short f2b(float f){
  union { float f; unsigned u; } v; v.f = f;
  unsigned r = v.u + 0x7FFFu + ((v.u >> 16) & 1u);
  return (unsigned short)(r >> 16);
}
__device__ __forceinline__ float b2f(unsigned short s){
  union { unsigned u; float f; } v; v.u = ((unsigned)s) << 16;
  return v.f;
}

// ---------------- precompute: Qm/Km/Vm = FE @ W_in^T  (3 x 64 x 256) ----------------
__global__ void k_pre_qkv(const float* __restrict__ FE, const float* __restrict__ W_in,
                          float* __restrict__ Qm, float* __restrict__ Km, float* __restrict__ Vm){
  int id = blockIdx.x*256 + threadIdx.x;      // 49152 = 3*64*256
  int part = id >> 14;
  int l = (id >> 8) & 63;
  int d = id & 255;
  const float4* fe = (const float4*)(FE + l*256);
  const float4* wr = (const float4*)(W_in + (part*256 + d)*256);
  float s = 0.f;
  #pragma unroll 8
  for (int k=0;k<64;k++){
    float4 a = fe[k], b = wr[k];
    s += a.x*b.x + a.y*b.y + a.z*b.z + a.w*b.w;
  }
  float* dst = (part==0)?Qm:((part==1)?Km:Vm);
  dst[l*256+d] = s;
}

// ---------------- precompute: G,u,w,s, abias ----------------
__global__ void k_pre_att(const float* __restrict__ Qm, const float* __restrict__ Km,
                          const float* __restrict__ b_in, const float* __restrict__ W_ao,
                          const float* __restrict__ b_ao,
                          float* __restrict__ G, float* __restrict__ U,
                          float* __restrict__ W, float* __restrict__ S,
                          float* __restrict__ abias){
  int id = blockIdx.x*256 + threadIdx.x;
  const float inv = 0.17677669529663687f;   // 1/sqrt(32)
  if (id < 32768){
    int h = id >> 12, lq = (id>>6)&63, lk = id&63;
    const float* qp = Qm + lq*256 + h*32;
    const float* kp = Km + lk*256 + h*32;
    float s=0.f;
    #pragma unroll
    for (int d=0;d<32;d++) s += qp[d]*kp[d];
    G[id] = s*inv;
  } else if (id < 33280){
    int j = id - 32768; int h = j>>6, lq = j&63;
    const float* qp = Qm + lq*256 + h*32;
    const float* bk = b_in + 256 + h*32;
    float s=0.f;
    #pragma unroll
    for (int d=0;d<32;d++) s += qp[d]*bk[d];
    U[j] = s*inv;
  } else if (id < 33792){
    int j = id - 33280; int h = j>>6, lk = j&63;
    const float* kp = Km + lk*256 + h*32;
    const float* bq = b_in + h*32;
    float s=0.f;
    #pragma unroll
    for (int d=0;d<32;d++) s += bq[d]*kp[d];
    W[j] = s*inv;
  } else if (id < 33800){
    int h = id - 33792;
    float s=0.f;
    #pragma unroll
    for (int d=0;d<32;d++) s += b_in[h*32+d]*b_in[256+h*32+d];
    S[h] = s*inv;
  } else if (id < 34056){
    int e = id - 33800;
    float s = b_ao[e];
    for (int d=0; d<256; d++) s += b_in[512+d]*W_ao[e*256+d];
    abias[e] = s;
  }
}

// ---------------- precompute: M2t[e][h*64+lk] = sum_d Vm[lk][h*32+d]*W_ao[e][h*32+d] ----------------
__global__ void k_pre_m2t(const float* __restrict__ Vm, const float* __restrict__ W_ao,
                          short* __restrict__ M2t){
  int id = blockIdx.x*256 + threadIdx.x;   // 131072 = 256*512
  int e = id >> 9, kk = id & 511;
  int h = kk >> 6, lk = kk & 63;
  const float* vp = Vm + lk*256 + h*32;
  const float* wp = W_ao + e*256 + h*32;
  float s=0.f;
  #pragma unroll
  for (int d=0;d<32;d++) s += vp[d]*wp[d];
  M2t[id] = (short)f2b(s);
}

// ---------------- precompute: bf16 weight copies ----------------
__global__ void k_cvt(const float* __restrict__ W1, const float* __restrict__ W2,
                      short* __restrict__ W1b, short* __restrict__ W2b){
  int id = blockIdx.x*256 + threadIdx.x;   // 524288
  if (id < 262144) W1b[id] = (short)f2b(W1[id]);
  else             W2b[id-262144] = (short)f2b(W2[id-262144]);
}

// ---------------- RNN scan + fourier -> z  (16 blocks x 64 threads) ----------------
__global__ void k_rnn(const float* __restrict__ x_cont, const float* __restrict__ z0,
                      const float* __restrict__ W_ih, const float* __restrict__ W_hh,
                      const float* __restrict__ b_ih, const float* __restrict__ b_hh,
                      const float* __restrict__ Uf, const float* __restrict__ Wfp,
                      const float* __restrict__ bfp, float* __restrict__ zout){
  int b = blockIdx.x;
  int l = threadIdx.x;
  __shared__ float h_sh[64];
  __shared__ float fh_sh[24];
  __shared__ float WfpT[24][64];
  float wr[64];
  #pragma unroll
  for (int j=0;j<64;j++) wr[j] = W_hh[l*64+j];
  #pragma unroll
  for (int j=0;j<24;j++) WfpT[j][l] = Wfp[l*24+j];
  float wih = W_ih[l];
  float bb  = b_ih[l] + b_hh[l];
  float bf  = bfp[l];
  float uf0=0,uf1=0,uf2=0,uf3=0;
  if (l < 24){ uf0=Uf[l*4+0]; uf1=Uf[l*4+1]; uf2=Uf[l*4+2]; uf3=Uf[l*4+3]; }
  h_sh[l] = z0[l];
  __syncthreads();
  const float* xb = x_cont + (size_t)b*128*97;
  for (int t=0;t<128;t++){
    float x0 = xb[t*97];
    float a0=0,a1=0,a2=0,a3=0;
    #pragma unroll
    for (int j=0;j<64;j+=4){
      a0 += wr[j  ]*h_sh[j  ];
      a1 += wr[j+1]*h_sh[j+1];
      a2 += wr[j+2]*h_sh[j+2];
      a3 += wr[j+3]*h_sh[j+3];
    }
    float hn = fmaxf(x0*wih + bb + ((a0+a1)+(a2+a3)), 0.f);
    float fh = 0.f;
    if (l < 24){
      const float* xf = xb + t*97 + 1 + l*4;
      fh = xf[0]*uf0 + xf[1]*uf1 + xf[2]*uf2 + xf[3]*uf3;
    }
    __syncthreads();
    h_sh[l] = hn;
    if (l < 24) fh_sh[l] = fh;
    __syncthreads();
    float zv = hn + bf;
    #pragma unroll
    for (int j=0;j<24;j++) zv += fh_sh[j]*WfpT[j][l];
    zout[((size_t)b*128 + t)*64 + l] = zv;
  }
}

// ---------------- fused per-token transformer block (2048 blocks x 256 thr) ----------------
// Transposed-acc formulation: D^T = W-side (A-frag) x activation (B-frag).
// acc[et][tt] element r maps to (e = cb+et*16+lg*4+r, tok = tt*16+lr).
__global__ __launch_bounds__(256, 3) void k_main(
  const float* __restrict__ zall, const float* __restrict__ G,
  const float* __restrict__ Ubuf, const float* __restrict__ Wbuf, const float* __restrict__ Sbuf,
  const float* __restrict__ abias, const short* __restrict__ M2t,
  const float* __restrict__ FE,
  const short* __restrict__ W1b, const float* __restrict__ b1,
  const short* __restrict__ W2b, const float* __restrict__ b2,
  const float* __restrict__ g1, const float* __restrict__ be1,
  const float* __restrict__ g2, const float* __restrict__ be2,
  const float* __restrict__ Wop, const float* __restrict__ bop,
  const float* __restrict__ Wg, const float* __restrict__ bg,
  const float* __restrict__ Amat, const float* __restrict__ cvec,
  float* __restrict__ out)
{
  const int n = blockIdx.x;
  const int tid = threadIdx.x;
  const int w = tid >> 6, lane = tid & 63, lg = lane >> 4, lr = lane & 15;
  const int cb = w * 64;           // this wave's e-range base

  __shared__ __align__(16) short t1_sh[64][264];   // 33792 B
  __shared__ __align__(16) char  upool[18432];     // union: attz[2][64][72] | mid[64][136] | red arrays
  __shared__ float z_sh[64];

  short (*attz)[64][72] = reinterpret_cast<short (*)[64][72]>(upool);
  short (*mid_sh)[136]  = reinterpret_cast<short (*)[136]>(upool);
  float* redA = reinterpret_cast<float*>(upool);            // [4][64]
  float* redB = reinterpret_cast<float*>(upool + 1024);     // [4][64]
  float* redC = reinterpret_cast<float*>(upool + 2048);     // [4][64]

  if (tid < 64) z_sh[tid] = zall[n*64 + tid];
  __syncthreads();

  const int lq = tid >> 2, q = tid & 3;
  const float zq = z_sh[lq];

  // ---------- attention (transposed): acc = (M2t rows) x (attz^T) ----------
  f32x4 acc[4][4];
  #pragma unroll
  for (int et=0;et<4;et++)
    #pragma unroll
    for (int tt=0;tt<4;tt++){ f32x4 zz = {0.f,0.f,0.f,0.f}; acc[et][tt] = zz; }

  for (int h=0; h<8; h++){
    float e[16];
    {
      const float* Gp = G + ((h*64 + lq)*64 + q*16);
      const float uh = Ubuf[h*64 + lq];
      const float sh = Sbuf[h];
      const float* wp = Wbuf + h*64 + q*16;
      float mx = -1e30f;
      #pragma unroll
      for (int i=0;i<16;i++){
        float zk = z_sh[q*16+i];
        float lv = zq*(zk*Gp[i] + uh) + (zk*wp[i] + sh);
        e[i] = lv;
        mx = fmaxf(mx, lv);
      }
      mx = fmaxf(mx, __shfl_xor(mx,1));
      mx = fmaxf(mx, __shfl_xor(mx,2));
      float sum = 0.f;
      #pragma unroll
      for (int i=0;i<16;i++){ e[i] = __expf(e[i]-mx); sum += e[i]; }
      sum += __shfl_xor(sum,1);
      sum += __shfl_xor(sum,2);
      float inv = 1.f/sum;
      #pragma unroll
      for (int i=0;i<16;i++) e[i] = e[i]*inv*z_sh[q*16+i];
    }
    {
      bf16x8 v0, v1;
      #pragma unroll
      for (int i=0;i<8;i++){ v0[i] = (short)f2b(e[i]); v1[i] = (short)f2b(e[8+i]); }
      *(bf16x8*)&attz[h&1][lq][q*16]     = v0;
      *(bf16x8*)&attz[h&1][lq][q*16 + 8] = v1;
    }
    __syncthreads();          // attz[h&1] ready; h-2's reads finished before barrier h-1
    #pragma unroll
    for (int ks=0; ks<2; ks++){
      bf16x8 am[4], bt[4];
      #pragma unroll
      for (int tt=0;tt<4;tt++) bt[tt] = *(const bf16x8*)&attz[h&1][tt*16+lr][ks*32 + lg*8];
      #pragma unroll
      for (int et=0;et<4;et++)
        am[et] = *(const bf16x8*)(M2t + (size_t)(cb+et*16+lr)*512 + h*64 + ks*32 + lg*8);
      #pragma unroll
      for (int et=0;et<4;et++)
        #pragma unroll
        for (int tt=0;tt<4;tt++)
          acc[et][tt] = __builtin_amdgcn_mfma_f32_16x16x32_bf16(am[et], bt[tt], acc[et][tt], 0,0,0);
    }
  }
  __syncthreads();   // A1: last attz reads done; upool becomes red region

  // ---------- t1 = LN(tokens + aop) ----------
  f32x4 ab4[4], g14[4], be14[4];
  #pragma unroll
  for (int et=0;et<4;et++){
    int e0 = cb + et*16 + lg*4;
    ab4[et]  = *(const f32x4*)(abias + e0);
    g14[et]  = *(const f32x4*)(g1 + e0);
    be14[et] = *(const f32x4*)(be1 + e0);
  }
  float sum1[4], ssq1[4];
  #pragma unroll
  for (int tt=0;tt<4;tt++){
    int tok = tt*16 + lr;
    float zt = z_sh[tok];
    float s = 0.f, sq = 0.f;
    #pragma unroll
    for (int et=0;et<4;et++){
      f32x4 fe = *(const f32x4*)(FE + (size_t)tok*256 + cb + et*16 + lg*4);
      #pragma unroll
      for (int r=0;r<4;r++){
        float v = acc[et][tt][r] + ab4[et][r] + zt*fe[r];
        acc[et][tt][r] = v; s += v; sq += v*v;
      }
    }
    s  += __shfl_xor(s,16);  s  += __shfl_xor(s,32);
    sq += __shfl_xor(sq,16); sq += __shfl_xor(sq,32);
    sum1[tt] = s; ssq1[tt] = sq;
  }
  if (lane < 16){
    #pragma unroll
    for (int tt=0;tt<4;tt++){ redA[w*64 + tt*16 + lane] = sum1[tt]; redB[w*64 + tt*16 + lane] = ssq1[tt]; }
  }
  __syncthreads();   // B1
  float mu1[4], rs1[4];
  #pragma unroll
  for (int tt=0;tt<4;tt++){
    int tok = tt*16 + lr;
    float s  = redA[tok] + redA[64+tok] + redA[128+tok] + redA[192+tok];
    float sq = redB[tok] + redB[64+tok] + redB[128+tok] + redB[192+tok];
    float m = s * (1.f/256.f);
    mu1[tt] = m;
    rs1[tt] = rsqrtf(sq*(1.f/256.f) - m*m + 1e-5f);
  }
  #pragma unroll
  for (int et=0;et<4;et++)
    #pragma unroll
    for (int tt=0;tt<4;tt++){
      s16x4 p;
      #pragma unroll
      for (int r=0;r<4;r++)
        p[r] = (short)f2b((acc[et][tt][r]-mu1[tt])*rs1[tt]*g14[et][r] + be14[et][r]);
      *(s16x4*)&t1_sh[tt*16+lr][cb + et*16 + lg*4] = p;
    }
  __syncthreads();   // C1: t1 ready

  // ---------- FFN: 8 chunks of 128 mid-channels ----------
  f32x4 outv[4][4];
  #pragma unroll
  for (int et=0;et<4;et++)
    #pragma unroll
    for (int tt=0;tt<4;tt++){ f32x4 zz = {0.f,0.f,0.f,0.f}; outv[et][tt] = zz; }

  for (int c=0; c<8; c++){
    f32x4 midv[2][4];
    #pragma unroll
    for (int ct=0;ct<2;ct++){
      f32x4 bi = *(const f32x4*)(b1 + c*128 + w*32 + ct*16 + lg*4);
      #pragma unroll
      for (int tt=0;tt<4;tt++) midv[ct][tt] = bi;
    }
    #pragma unroll
    for (int ks=0; ks<8; ks++){
      bf16x8 bt[4], aw[2];
      #pragma unroll
      for (int tt=0;tt<4;tt++) bt[tt] = *(const bf16x8*)&t1_sh[tt*16+lr][ks*32 + lg*8];
      #pragma unroll
      for (int ct=0;ct<2;ct++)
        aw[ct] = *(const bf16x8*)(W1b + (size_t)(c*128 + w*32 + ct*16 + lr)*256 + ks*32 + lg*8);
      #pragma unroll
      for (int ct=0;ct<2;ct++)
        #pragma unroll
        for (int tt=0;tt<4;tt++)
          midv[ct][tt] = __builtin_amdgcn_mfma_f32_16x16x32_bf16(aw[ct], bt[tt], midv[ct][tt], 0,0,0);
    }
    __syncthreads();       // prior FFN2 reads of mid done
    #pragma unroll
    for (int ct=0;ct<2;ct++)
      #pragma unroll
      for (int tt=0;tt<4;tt++){
        s16x4 p;
        #pragma unroll
        for (int r=0;r<4;r++) p[r] = (short)f2b(fmaxf(midv[ct][tt][r], 0.f));
        *(s16x4*)&mid_sh[tt*16+lr][w*32 + ct*16 + lg*4] = p;
      }
    __syncthreads();
    #pragma unroll
    for (int ks=0; ks<4; ks++){
      bf16x8 bm[4], aw2[4];
      #pragma unroll
      for (int tt=0;tt<4;tt++) bm[tt] = *(const bf16x8*)&mid_sh[tt*16+lr][ks*32 + lg*8];
      #pragma unroll
      for (int et=0;et<4;et++)
        aw2[et] = *(const bf16x8*)(W2b + (size_t)(cb+et*16+lr)*1024 + c*128 + ks*32 + lg*8);
      #pragma unroll
      for (int et=0;et<4;et++)
        #pragma unroll
        for (int tt=0;tt<4;tt++)
          outv[et][tt] = __builtin_amdgcn_mfma_f32_16x16x32_bf16(aw2[et], bm[tt], outv[et][tt], 0,0,0);
    }
  }

  // ---------- t2 = LN(t1 + ffn), delta, z_out, o ----------
  f32x4 b24[4];
  #pragma unroll
  for (int et=0;et<4;et++) b24[et] = *(const f32x4*)(b2 + cb + et*16 + lg*4);
  float sum2[4], ssq2[4];
  #pragma unroll
  for (int tt=0;tt<4;tt++){
    int tok = tt*16 + lr;
    float s = 0.f, sq = 0.f;
    #pragma unroll
    for (int et=0;et<4;et++){
      s16x4 t1v = *(const s16x4*)&t1_sh[tok][cb + et*16 + lg*4];
      #pragma unroll
      for (int r=0;r<4;r++){
        float v = outv[et][tt][r] + b24[et][r] + b2f((unsigned short)t1v[r]);
        outv[et][tt][r] = v; s += v; sq += v*v;
      }
    }
    s  += __shfl_xor(s,16);  s  += __shfl_xor(s,32);
    sq += __shfl_xor(sq,16); sq += __shfl_xor(sq,32);
    sum2[tt] = s; ssq2[tt] = sq;
  }
  __syncthreads();   // A2: FFN2 mid reads done; red region free
  if (lane < 16){
    #pragma unroll
    for (int tt=0;tt<4;tt++){ redA[w*64 + tt*16 + lane] = sum2[tt]; redB[w*64 + tt*16 + lane] = ssq2[tt]; }
  }
  __syncthreads();   // B2

  float gate = 0.f;
  if (tid < 64){
    float gacc = bg[tid];
    const f32x4* wgr = (const f32x4*)(Wg + tid*64);
    #pragma unroll
    for (int j=0;j<16;j++){
      f32x4 wv = wgr[j];
      f32x4 zv = *(const f32x4*)(z_sh + j*4);
      gacc += wv[0]*zv[0] + wv[1]*zv[1] + wv[2]*zv[2] + wv[3]*zv[3];
    }
    gate = 1.f/(1.f + __expf(-gacc));
  }

  f32x4 g24[4], be24[4], wop4[4];
  #pragma unroll
  for (int et=0;et<4;et++){
    int e0 = cb + et*16 + lg*4;
    g24[et]  = *(const f32x4*)(g2 + e0);
    be24[et] = *(const f32x4*)(be2 + e0);
    wop4[et] = *(const f32x4*)(Wop + e0);
  }
  #pragma unroll
  for (int tt=0;tt<4;tt++){
    int tok = tt*16 + lr;
    float s  = redA[tok] + redA[64+tok] + redA[128+tok] + redA[192+tok];
    float sq = redB[tok] + redB[64+tok] + redB[128+tok] + redB[192+tok];
    float m = s * (1.f/256.f);
    float rs = rsqrtf(sq*(1.f/256.f) - m*m + 1e-5f);
    float d = 0.f;
    #pragma unroll
    for (int et=0;et<4;et++)
      #pragma unroll
      for (int r=0;r<4;r++){
        float t2 = (outv[et][tt][r]-m)*rs*g24[et][r] + be24[et][r];
        d += t2*wop4[et][r];
      }
    d += __shfl_xor(d,16); d += __shfl_xor(d,32);
    if (lane < 16) redC[w*64 + tt*16 + lane] = d;
  }
  __syncthreads();   // D2
  if (tid < 64){
    float delta = redC[tid] + redC[64+tid] + redC[128+tid] + redC[192+tid] + bop[0];
    float zo = z_sh[tid] + gate*delta;
    out[49152 + (size_t)n*64 + tid] = zo;
    z_sh[tid] = zo;
  }
  __syncthreads();   // E2
  if (tid < 24){
    const float* ar = Amat + tid*64;
    float s = cvec[tid];
    #pragma unroll
    for (int j=0;j<64;j++) s += z_sh[j]*ar[j];
    out[(size_t)n*24 + tid] = s;
  }
}

extern "C" void kernel_launch(void* const* d_in, const int* in_sizes, int n_in,
                              void* d_out, int out_size, void* d_ws, size_t ws_size,
                              hipStream_t stream) {
  const float* x_cont = (const float*)d_in[0];
  const float* z0    = (const float*)d_in[1];
  const float* W_ih  = (const float*)d_in[2];
  const float* W_hh  = (const float*)d_in[3];
  const float* b_ih  = (const float*)d_in[4];
  const float* b_hh  = (const float*)d_in[5];
  const float* Uf    = (const float*)d_in[6];
  const float* Wfp   = (const float*)d_in[7];
  const float* bfp   = (const float*)d_in[8];
  const float* FE    = (const float*)d_in[9];
  const float* W_in  = (const float*)d_in[10];
  const float* b_in  = (const float*)d_in[11];
  const float* W_ao  = (const float*)d_in[12];
  const float* b_ao  = (const float*)d_in[13];
  const float* g1    = (const float*)d_in[14];
  const float* be1   = (const float*)d_in[15];
  const float* W1    = (const float*)d_in[16];
  const float* b1    = (const float*)d_in[17];
  const float* W2    = (const float*)d_in[18];
  const float* b2    = (const float*)d_in[19];
  const float* g2    = (const float*)d_in[20];
  const float* be2   = (const float*)d_in[21];
  const float* Wop   = (const float*)d_in[22];
  const float* bop   = (const float*)d_in[23];
  const float* Wg    = (const float*)d_in[24];
  const float* bg    = (const float*)d_in[25];
  const float* Amat  = (const float*)d_in[26];
  const float* cvec  = (const float*)d_in[27];
  float* out = (float*)d_out;
  char* ws = (char*)d_ws;

  float* z    = (float*)(ws + 0);         // 2048*64*4
  float* Qm   = (float*)(ws + 524288);
  float* Km   = (float*)(ws + 589824);
  float* Vm   = (float*)(ws + 655360);
  float* G    = (float*)(ws + 720896);    // 8*64*64*4
  float* U    = (float*)(ws + 851968);
  float* Wb   = (float*)(ws + 854016);
  float* S    = (float*)(ws + 856064);
  float* ab   = (float*)(ws + 856320);
  short* M2t  = (short*)(ws + 857344);    // 256*512*2
  short* W1b  = (short*)(ws + 1119488);   // 1024*256*2
  short* W2b  = (short*)(ws + 1643776);   // 256*1024*2

  hipLaunchKernelGGL(k_pre_qkv, dim3(192), dim3(256), 0, stream, FE, W_in, Qm, Km, Vm);
  hipLaunchKernelGGL(k_pre_att, dim3(134), dim3(256), 0, stream, Qm, Km, b_in, W_ao, b_ao, G, U, Wb, S, ab);
  hipLaunchKernelGGL(k_pre_m2t, dim3(512), dim3(256), 0, stream, Vm, W_ao, M2t);
  hipLaunchKernelGGL(k_cvt, dim3(2048), dim3(256), 0, stream, W1, W2, W1b, W2b);
  hipLaunchKernelGGL(k_rnn, dim3(16), dim3(64), 0, stream, x_cont, z0, W_ih, W_hh, b_ih, b_hh, Uf, Wfp, bfp, z);
  hipLaunchKernelGGL(k_main, dim3(2048), dim3(256), 0, stream, z, G, U, Wb, S, ab, M2t, FE,
                     W1b, b1, W2b, b2, g1, be1, g2, be2, Wop, bop, Wg, bg, Amat, cvec, out);
}